// Round 1
// baseline (144.637 us; speedup 1.0000x reference)
//
#include <hip/hip_runtime.h>

// LogicGatedSNN fused kernel.
// Outputs concatenated in d_out (all float32):
//   [0, 8192)                 spikes
//   [8192, 16384)             new_v_mem
//   [16384, 16384+8192*8192)  new_trace (row-major [out][in])

#define IN_F 8192
#define OUT_F 8192
#define THR_F 50.0f
#define BLOCK 256
// float4 elements per row = 8192/4 = 2048; per-thread = 2048/256 = 8
#define V4_PER_THREAD 8

__global__ __launch_bounds__(BLOCK) void snn_fused_kernel(
    const float* __restrict__ x,        // [IN_F] spike_input (flattened)
    const float* __restrict__ syn,      // [OUT_F * IN_F]
    const float* __restrict__ vmem_in,  // [OUT_F]
    const float* __restrict__ thr,      // [OUT_F]
    const float* __restrict__ trace_in, // [OUT_F * IN_F]
    float* __restrict__ out_spikes,     // [OUT_F]
    float* __restrict__ out_vmem,       // [OUT_F]
    float* __restrict__ out_trace)      // [OUT_F * IN_F]
{
    const int o = blockIdx.x;
    const int tid = threadIdx.x;

    const float4* __restrict__ syn4 =
        reinterpret_cast<const float4*>(syn + (size_t)o * IN_F);
    const float4* __restrict__ x4 = reinterpret_cast<const float4*>(x);

    // ---- Phase 1: row dot of binary weight mask with binary input ----
    float partial = 0.0f;
#pragma unroll
    for (int j = 0; j < V4_PER_THREAD; ++j) {
        const int idx = tid + j * BLOCK;
        const float4 s = syn4[idx];
        const float4 xv = x4[idx];
        partial += (s.x > THR_F) ? xv.x : 0.0f;
        partial += (s.y > THR_F) ? xv.y : 0.0f;
        partial += (s.z > THR_F) ? xv.z : 0.0f;
        partial += (s.w > THR_F) ? xv.w : 0.0f;
    }

    // wave-64 butterfly reduce
#pragma unroll
    for (int off = 32; off > 0; off >>= 1)
        partial += __shfl_down(partial, off, 64);

    __shared__ float wsum[BLOCK / 64];
    __shared__ float s_spike;
    const int wid = tid >> 6;
    const int lane = tid & 63;
    if (lane == 0) wsum[wid] = partial;
    __syncthreads();

    if (tid == 0) {
        float cur = wsum[0] + wsum[1] + wsum[2] + wsum[3];
        const float v = vmem_in[o] * 0.7f + cur;
        const float sp = (v >= thr[o]) ? 1.0f : 0.0f;
        out_spikes[o] = sp;
        out_vmem[o] = v * (1.0f - sp) * 0.5f;
        s_spike = sp;
    }
    __syncthreads();
    const float sp = s_spike;

    // ---- Phase 2: eligibility trace update (streaming) ----
    const float4* __restrict__ tr4 =
        reinterpret_cast<const float4*>(trace_in + (size_t)o * IN_F);
    float4* __restrict__ ot4 =
        reinterpret_cast<float4*>(out_trace + (size_t)o * IN_F);
#pragma unroll
    for (int j = 0; j < V4_PER_THREAD; ++j) {
        const int idx = tid + j * BLOCK;
        const float4 t = tr4[idx];
        const float4 xv = x4[idx];
        float4 r;
        r.x = t.x * 0.8f + sp * xv.x;
        r.y = t.y * 0.8f + sp * xv.y;
        r.z = t.z * 0.8f + sp * xv.z;
        r.w = t.w * 0.8f + sp * xv.w;
        ot4[idx] = r;
    }
}

extern "C" void kernel_launch(void* const* d_in, const int* in_sizes, int n_in,
                              void* d_out, int out_size, void* d_ws, size_t ws_size,
                              hipStream_t stream) {
    const float* x        = (const float*)d_in[0]; // spike_input [1,8192]
    const float* syn      = (const float*)d_in[1]; // synapse_states [8192,8192]
    const float* vmem     = (const float*)d_in[2]; // membrane_potential [8192]
    const float* thr      = (const float*)d_in[3]; // adaptive_threshold [8192]
    const float* trace    = (const float*)d_in[4]; // eligibility_trace [8192,8192]

    float* out = (float*)d_out;
    float* out_spikes = out;                 // [8192]
    float* out_vmem   = out + OUT_F;         // [8192]
    float* out_trace  = out + 2 * OUT_F;     // [8192*8192]

    snn_fused_kernel<<<OUT_F, BLOCK, 0, stream>>>(
        x, syn, vmem, thr, trace, out_spikes, out_vmem, out_trace);
}

// Round 3
// 119.121 us; speedup vs baseline: 1.2142x; 1.2142x over previous
//
#include <hip/hip_runtime.h>

// LogicGatedSNN fused kernel, v2b: all loads issued before the barrier;
// native ext_vector float4 so nontemporal builtins accept the pointers.
// Outputs concatenated in d_out (all float32):
//   [0, 8192)                 spikes
//   [8192, 16384)             new_v_mem
//   [16384, 16384+8192*8192)  new_trace (row-major [out][in])

#define IN_F 8192
#define OUT_F 8192
#define THR_F 50.0f
#define BLOCK 256
// float4 elements per row = 8192/4 = 2048; per-thread = 2048/256 = 8
#define V4_PER_THREAD 8

typedef float f4 __attribute__((ext_vector_type(4)));

__global__ __launch_bounds__(BLOCK) void snn_fused_kernel(
    const float* __restrict__ x,        // [IN_F] spike_input (flattened)
    const float* __restrict__ syn,      // [OUT_F * IN_F]
    const float* __restrict__ vmem_in,  // [OUT_F]
    const float* __restrict__ thr,      // [OUT_F]
    const float* __restrict__ trace_in, // [OUT_F * IN_F]
    float* __restrict__ out_spikes,     // [OUT_F]
    float* __restrict__ out_vmem,       // [OUT_F]
    float* __restrict__ out_trace)      // [OUT_F * IN_F]
{
    const int o = blockIdx.x;
    const int tid = threadIdx.x;
    const size_t rowoff = (size_t)o * IN_F;

    const f4* __restrict__ syn4 = reinterpret_cast<const f4*>(syn + rowoff);
    const f4* __restrict__ x4   = reinterpret_cast<const f4*>(x);
    const f4* __restrict__ tr4  = reinterpret_cast<const f4*>(trace_in + rowoff);
    f4* __restrict__ ot4        = reinterpret_cast<f4*>(out_trace + rowoff);

    // ---- Issue ALL loads up front: trace row -> registers (needed only
    // after the barrier), syn+x -> dot product. Up to 24 float4 loads in
    // flight per thread; trace loads' latency hides under reduce+barrier. ----
    f4 tr[V4_PER_THREAD];
#pragma unroll
    for (int j = 0; j < V4_PER_THREAD; ++j) {
        const int idx = tid + j * BLOCK;
        tr[j] = __builtin_nontemporal_load(&tr4[idx]);
    }

    float partial = 0.0f;
#pragma unroll
    for (int j = 0; j < V4_PER_THREAD; ++j) {
        const int idx = tid + j * BLOCK;
        const f4 s  = syn4[idx];
        const f4 xv = x4[idx];
        partial += (s.x > THR_F) ? xv.x : 0.0f;
        partial += (s.y > THR_F) ? xv.y : 0.0f;
        partial += (s.z > THR_F) ? xv.z : 0.0f;
        partial += (s.w > THR_F) ? xv.w : 0.0f;
    }

    // wave-64 butterfly reduce
#pragma unroll
    for (int off = 32; off > 0; off >>= 1)
        partial += __shfl_down(partial, off, 64);

    __shared__ float wsum[BLOCK / 64];
    __shared__ float s_spike;
    const int wid = tid >> 6;
    const int lane = tid & 63;
    if (lane == 0) wsum[wid] = partial;
    __syncthreads();

    if (tid == 0) {
        const float cur = wsum[0] + wsum[1] + wsum[2] + wsum[3];
        const float v = vmem_in[o] * 0.7f + cur;
        const float sp = (v >= thr[o]) ? 1.0f : 0.0f;
        out_spikes[o] = sp;
        out_vmem[o] = v * (1.0f - sp) * 0.5f;
        s_spike = sp;
    }
    __syncthreads();
    const float sp = s_spike;

    // ---- Trace update: FMA on register-held trace + x (L1-hit reload),
    // nontemporal streaming stores. ----
#pragma unroll
    for (int j = 0; j < V4_PER_THREAD; ++j) {
        const int idx = tid + j * BLOCK;
        const f4 xv = x4[idx];
        f4 r;
        r.x = tr[j].x * 0.8f + sp * xv.x;
        r.y = tr[j].y * 0.8f + sp * xv.y;
        r.z = tr[j].z * 0.8f + sp * xv.z;
        r.w = tr[j].w * 0.8f + sp * xv.w;
        __builtin_nontemporal_store(r, &ot4[idx]);
    }
}

extern "C" void kernel_launch(void* const* d_in, const int* in_sizes, int n_in,
                              void* d_out, int out_size, void* d_ws, size_t ws_size,
                              hipStream_t stream) {
    const float* x     = (const float*)d_in[0]; // spike_input [1,8192]
    const float* syn   = (const float*)d_in[1]; // synapse_states [8192,8192]
    const float* vmem  = (const float*)d_in[2]; // membrane_potential [8192]
    const float* thr   = (const float*)d_in[3]; // adaptive_threshold [8192]
    const float* trace = (const float*)d_in[4]; // eligibility_trace [8192,8192]

    float* out = (float*)d_out;
    float* out_spikes = out;             // [8192]
    float* out_vmem   = out + OUT_F;     // [8192]
    float* out_trace  = out + 2 * OUT_F; // [8192*8192]

    snn_fused_kernel<<<OUT_F, BLOCK, 0, stream>>>(
        x, syn, vmem, thr, trace, out_spikes, out_vmem, out_trace);
}